// Round 5
// baseline (346.974 us; speedup 1.0000x reference)
//
#include <hip/hip_runtime.h>
#include <hip/hip_cooperative_groups.h>

namespace cg = cooperative_groups;

// Problem constants (B=32, C=3, H=480, W=640)
#define HW      307200     // H*W
#define HW4     76800      // HW/4 (float4 groups per plane)
#define CHW     921600     // 3*HW
#define BPB     30         // blocks per batch: 30*256*10 == HW4 exactly
#define GPT     10         // float4 groups per thread per plane

// native clang vector type — required by __builtin_nontemporal_store
typedef float vfloat4 __attribute__((ext_vector_type(4)));

struct RGB { float r, g, b; };

// ---------------------------------------------------------------------------
// brightness -> contrast blend -> saturation blend -> hue, one pixel
// ---------------------------------------------------------------------------
__device__ __forceinline__ RGB cr_process(
    float r, float g, float b,
    float bf, float cf, float sf, float hf, float cmean)
{
    // brightness
    r = fminf(fmaxf(r * bf, 0.0f), 1.0f);
    g = fminf(fmaxf(g * bf, 0.0f), 1.0f);
    b = fminf(fmaxf(b * bf, 0.0f), 1.0f);
    // contrast: cmean = (1-cf)*mean precomputed (uniform)
    r = fminf(fmaxf(cf * r + cmean, 0.0f), 1.0f);
    g = fminf(fmaxf(cf * g + cmean, 0.0f), 1.0f);
    b = fminf(fmaxf(cf * b + cmean, 0.0f), 1.0f);
    // saturation: blend with per-pixel gray
    float gray = 0.299f * r + 0.587f * g + 0.114f * b;
    float oms = (1.0f - sf) * gray;
    r = fminf(fmaxf(sf * r + oms, 0.0f), 1.0f);
    g = fminf(fmaxf(sf * g + oms, 0.0f), 1.0f);
    b = fminf(fmaxf(sf * b + oms, 0.0f), 1.0f);

    // hue adjust (RGB -> h,s,v -> shift h -> RGB)
    float maxc = fmaxf(r, fmaxf(g, b));
    float minc = fminf(r, fminf(g, b));
    float v  = maxc;
    float cr = maxc - minc;
    float crd = (cr == 0.0f) ? 1.0f : cr;
    float invcrd = 1.0f / crd;
    float md = (maxc == 0.0f) ? 1.0f : maxc;
    float s = cr / md;
    float rc = (maxc - r) * invcrd;
    float gc = (maxc - g) * invcrd;
    float bc = (maxc - b) * invcrd;

    float h = (maxc == r) ? (bc - gc)
            : ((maxc == g) ? (2.0f + rc - bc)
                           : (4.0f + gc - rc));
    h = h * (1.0f / 6.0f);
    h = h - floorf(h);      // python-style mod 1
    h = h + hf;
    h = h - floorf(h);

    float i6 = h * 6.0f;
    float fi = floorf(i6);
    float f  = i6 - fi;
    int i = ((int)fi) % 6;   // fi in [0,6]; 6 aliases to 0 with f==0 (continuous)

    float p = v * (1.0f - s);
    float q = v * (1.0f - f * s);
    float t = v * (1.0f - (1.0f - f) * s);

    RGB o;
    o.r = (i == 0 || i == 5) ? v : (i == 1 ? q : (i == 4 ? t : p));
    o.g = (i == 1 || i == 2) ? v : (i == 0 ? t : (i == 3 ? q : p));
    o.b = (i == 3 || i == 4) ? v : (i == 5 ? q : (i == 2 ? t : p));
    return o;
}

// ---------------------------------------------------------------------------
// Fused cooperative kernel:
//   phase 1: per-block partial sum of gray(clip(x*bf)) -> ws[b*BPB+blk]
//   grid.sync()
//   phase 2: per-block mean broadcast, elementwise pipeline, nt stores
// Each block owns 2560 contiguous float4-groups of one batch (10/thread).
// ---------------------------------------------------------------------------
__global__ __launch_bounds__(256) void cr_fused(
    const float* __restrict__ x,
    const float* __restrict__ bright,
    const float* __restrict__ contrast,
    const float* __restrict__ sat,
    const float* __restrict__ hue,
    float* __restrict__ part_ws,
    float* __restrict__ out,
    int ns)
{
    int b   = blockIdx.x / BPB;         // uniform per block
    int blk = blockIdx.x % BPB;
    int b_in = (ns == 1) ? b : (b / ns);
    int base = blk * (256 * GPT) + threadIdx.x;

    const vfloat4* rp = (const vfloat4*)(x + (size_t)b_in * CHW);
    const vfloat4* gp = rp + HW4;
    const vfloat4* bp = gp + HW4;

    float bf = bright[b];

    // ---- phase 1: brightness-clipped gray partial sum ----
    float acc = 0.0f;
    #pragma unroll
    for (int it = 0; it < GPT; ++it) {
        int p = base + it * 256;
        vfloat4 r  = rp[p];
        vfloat4 g  = gp[p];
        vfloat4 bl = bp[p];
        #pragma unroll
        for (int k = 0; k < 4; ++k) {
            float rr = fminf(fmaxf(r[k]  * bf, 0.0f), 1.0f);
            float gg = fminf(fmaxf(g[k]  * bf, 0.0f), 1.0f);
            float bb = fminf(fmaxf(bl[k] * bf, 0.0f), 1.0f);
            acc += 0.299f * rr + 0.587f * gg + 0.114f * bb;
        }
    }

    #pragma unroll
    for (int off = 32; off > 0; off >>= 1)
        acc += __shfl_down(acc, off);

    __shared__ float wsum[4];
    __shared__ float smean;
    int lane = threadIdx.x & 63;
    int wave = threadIdx.x >> 6;
    if (lane == 0) wsum[wave] = acc;
    __syncthreads();
    if (threadIdx.x == 0)
        part_ws[b * BPB + blk] = wsum[0] + wsum[1] + wsum[2] + wsum[3];

    // ---- grid-wide barrier: all partials visible ----
    cg::this_grid().sync();

    // ---- phase 2: mean broadcast + apply ----
    if (threadIdx.x < 64) {
        float v = (threadIdx.x < BPB) ? part_ws[b * BPB + threadIdx.x] : 0.0f;
        #pragma unroll
        for (int off = 32; off > 0; off >>= 1)
            v += __shfl_down(v, off);
        if (threadIdx.x == 0) smean = v * (1.0f / (float)HW);
    }
    __syncthreads();

    float cf = contrast[b];
    float sf = sat[b];
    float hf = hue[b];
    float cmean = (1.0f - cf) * smean;

    vfloat4* orp = (vfloat4*)(out + (size_t)b * CHW);
    vfloat4* ogp = orp + HW4;
    vfloat4* obp = ogp + HW4;

    #pragma unroll 2
    for (int it = 0; it < GPT; ++it) {
        int p = base + it * 256;
        vfloat4 r  = rp[p];     // L3-resident from phase 1
        vfloat4 g  = gp[p];
        vfloat4 bl = bp[p];
        vfloat4 ro, go, bo;
        #pragma unroll
        for (int k = 0; k < 4; ++k) {
            RGB o = cr_process(r[k], g[k], bl[k], bf, cf, sf, hf, cmean);
            ro[k] = o.r;
            go[k] = o.g;
            bo[k] = o.b;
        }
        // nt stores: out never re-read; keep x resident in L3
        __builtin_nontemporal_store(ro, &orp[p]);
        __builtin_nontemporal_store(go, &ogp[p]);
        __builtin_nontemporal_store(bo, &obp[p]);
    }
}

extern "C" void kernel_launch(void* const* d_in, const int* in_sizes, int n_in,
                              void* d_out, int out_size, void* d_ws, size_t ws_size,
                              hipStream_t stream) {
    const float* x  = (const float*)d_in[0];
    const float* bf = (const float*)d_in[1];
    const float* cf = (const float*)d_in[2];
    const float* sf = (const float*)d_in[3];
    const float* hf = (const float*)d_in[4];
    float* out = (float*)d_out;

    int ns = out_size / in_sizes[0];
    if (ns < 1) ns = 1;
    int B_out = out_size / CHW;

    float* part_ws = (float*)d_ws;   // B_out * BPB floats, fully rewritten each call

    void* args[] = { (void*)&x, (void*)&bf, (void*)&cf, (void*)&sf, (void*)&hf,
                     (void*)&part_ws, (void*)&out, (void*)&ns };
    hipLaunchCooperativeKernel((void*)cr_fused,
                               dim3(B_out * BPB), dim3(256),
                               args, 0, stream);
}